// Round 11
// baseline (169.640 us; speedup 1.0000x reference)
//
#include <hip/hip_runtime.h>

#define N_ 4096
#define C_ 256
#define H_ 16
#define D_ 64
#define HD_ 1024

typedef __attribute__((ext_vector_type(8))) _Float16 f16x8;
typedef __attribute__((ext_vector_type(4))) _Float16 f16x4;
typedef __attribute__((ext_vector_type(4))) float f32x4;

__device__ __forceinline__ void gload16(const void* g, void* l) {
    __builtin_amdgcn_global_load_lds(
        (const __attribute__((address_space(1))) unsigned int*)g,
        (__attribute__((address_space(3))) unsigned int*)l, 16, 0, 0);
}

// ---------------------------------------------------------------------------
// Kernel 0: weight conversion only (R11: X conversion folded into proj).
//   [0,256):   Wq..Wg [256][1024] -> WTf [4][1024][256] fp16 (transposed)
//   [256,320): Wo [1024][256] -> WoTf [256][1024] fp16 (transposed)
// ---------------------------------------------------------------------------
__global__ __launch_bounds__(256) void convert_kernel(
    const float* __restrict__ Wq, const float* __restrict__ Wk,
    const float* __restrict__ Wv, const float* __restrict__ Wg,
    const float* __restrict__ Wo,
    _Float16* __restrict__ WTf, _Float16* __restrict__ WoTf)
{
    __shared__ float ts[64][65];
    const int b = blockIdx.x;
    const int tid = threadIdx.x;

    const float* src;
    _Float16* df;
    int srcC, dstC, r0, c0;
    if (b < 256) {
        const int widx = b >> 6;
        const int tile = b & 63;
        src = (widx == 0) ? Wq : (widx == 1) ? Wk : (widx == 2) ? Wv : Wg;
        df = WTf + (size_t)widx * 262144;
        srcC = 1024; dstC = 256;
        r0 = (tile >> 4) * 64;
        c0 = (tile & 15) * 64;
    } else {
        const int tile = b - 256;
        src = Wo; df = WoTf;
        srcC = 256; dstC = 1024;
        r0 = (tile >> 2) * 64;
        c0 = (tile & 3) * 64;
    }
    {
        const int r = tid >> 2;
        const int cch = (tid & 3) * 16;
#pragma unroll
        for (int q = 0; q < 4; ++q) {
            float4 v = *(const float4*)&src[(size_t)(r0 + r) * srcC + c0 + cch + q * 4];
            ts[r][cch + q * 4 + 0] = v.x;
            ts[r][cch + q * 4 + 1] = v.y;
            ts[r][cch + q * 4 + 2] = v.z;
            ts[r][cch + q * 4 + 3] = v.w;
        }
    }
    __syncthreads();
    {
        const int c = tid >> 2;
        const int rch = (tid & 3) * 16;
#pragma unroll
        for (int q = 0; q < 4; ++q) {
            f16x4 fv;
#pragma unroll
            for (int j = 0; j < 4; ++j)
                fv[j] = (_Float16)ts[rch + q * 4 + j][c];
            *(f16x4*)&df[(size_t)(c0 + c) * dstC + r0 + rch + q * 4] = fv;
        }
    }
}

// ---------------------------------------------------------------------------
// Kernel 1: projections via fp16 MFMA. 128x128 tile, BK=64, XOR-8 swizzle,
// XCD swizzle, LDS-routed vectorized epilogue. R11: A operand read directly
// from fp32 X (q_x/kv_x) with inline fp16 conversion + ds_write_b128 into
// the same swizzled LDS layout -- removes the Xf convert pass + roundtrip.
// B stays gload16 from preconverted WTf (transpose needs the separate pass).
// ---------------------------------------------------------------------------
__global__ __launch_bounds__(256) void proj_mfma(
    const float* __restrict__ q_x, const float* __restrict__ kv_x,
    const _Float16* __restrict__ WTf,
    _Float16* __restrict__ qh, _Float16* __restrict__ kh,
    _Float16* __restrict__ vh, _Float16* __restrict__ gh)
{
    __shared__ __align__(16) char psmem[34816];
    _Float16* As = (_Float16*)psmem;
    _Float16* Bs = (_Float16*)(psmem + 16384);

    const int lb  = blockIdx.x;
    const int xcd = lb & 7;
    const int gr  = (lb >> 6) * 8 + xcd;    // 0..127 -> (g, row-tile)
    const int g   = gr >> 5;
    const int m0  = (gr & 31) * 128;
    const int c0  = ((lb >> 3) & 7) * 128;

    const float* A32 = (g == 1 || g == 2) ? kv_x : q_x;
    const _Float16* B = WTf + (size_t)g * 262144;

    const int tid  = threadIdx.x;
    const int wave = tid >> 6;
    const int lane = tid & 63;
    const int wr   = wave >> 1;
    const int wc   = wave & 1;
    const int frow = lane & 15;
    const int grp  = lane >> 4;

    f32x4 acc[4][4];
#pragma unroll
    for (int i = 0; i < 4; ++i)
#pragma unroll
        for (int j = 0; j < 4; ++j) acc[i][j] = (f32x4){0.f, 0.f, 0.f, 0.f};

    const int srow = tid >> 3;              // 0..31
    const int sch  = tid & 7;               // chunk 0..7

    for (int kt = 0; kt < 256; kt += 64) {
        __syncthreads();
#pragma unroll
        for (int p = 0; p < 4; ++p) {
            const int row = p * 32 + srow;
            const int koff = kt + ((sch ^ (row & 7)) << 3);
            // B: async fp16 staging
            gload16(B + (size_t)(c0 + row) * 256 + koff, (char*)Bs + p * 4096 + tid * 16);
            // A: fp32 load -> fp16 pack -> LDS (same swizzled layout)
            const float* srcp = A32 + (size_t)(m0 + row) * 256 + koff;
            float4 x0 = *(const float4*)srcp;
            float4 x1 = *(const float4*)(srcp + 4);
            f16x8 pk;
            pk[0] = (_Float16)x0.x; pk[1] = (_Float16)x0.y;
            pk[2] = (_Float16)x0.z; pk[3] = (_Float16)x0.w;
            pk[4] = (_Float16)x1.x; pk[5] = (_Float16)x1.y;
            pk[6] = (_Float16)x1.z; pk[7] = (_Float16)x1.w;
            *(f16x8*)((char*)As + p * 4096 + tid * 16) = pk;
        }
        __syncthreads();

#pragma unroll
        for (int ks = 0; ks < 2; ++ks) {
            f16x8 af[4], bf[4];
#pragma unroll
            for (int f = 0; f < 4; ++f) {
                const int ra = wr * 64 + f * 16 + frow;
                const int rb = wc * 64 + f * 16 + frow;
                af[f] = *(const f16x8*)((char*)As + ra * 128 + (((ks * 4 + grp) ^ (ra & 7)) << 4));
                bf[f] = *(const f16x8*)((char*)Bs + rb * 128 + (((ks * 4 + grp) ^ (rb & 7)) << 4));
            }
#pragma unroll
            for (int i = 0; i < 4; ++i)
#pragma unroll
                for (int j = 0; j < 4; ++j)
                    acc[i][j] = __builtin_amdgcn_mfma_f32_16x16x32_f16(af[i], bf[j], acc[i][j], 0, 0, 0);
        }
    }

    __syncthreads();
    _Float16* Epi = (_Float16*)psmem;        // [128][136] fp16
    {
        const float scale = (g == 0) ? 0.125f : 1.f;
#pragma unroll
        for (int i = 0; i < 4; ++i)
#pragma unroll
            for (int j = 0; j < 4; ++j) {
                const int rr = wr * 64 + i * 16 + grp * 4;
                const int cc = wc * 64 + j * 16 + frow;
#pragma unroll
                for (int v = 0; v < 4; ++v) {
                    float x = acc[i][j][v];
                    x = (g == 3) ? 1.f / (1.f + __expf(-x)) : x * scale;
                    Epi[(rr + v) * 136 + cc] = (_Float16)x;
                }
            }
    }
    __syncthreads();
    {
        const int ch   = tid & 15;
        const int head = ch >> 3;
        const int e8   = (ch & 7) * 8;
#pragma unroll
        for (int p = 0; p < 8; ++p) {
            const int r = p * 16 + (tid >> 4);
            const f16x8 val = *(const f16x8*)&Epi[r * 136 + head * 64 + e8];
            if (g == 3) {
                *(f16x8*)&gh[(size_t)(m0 + r) * HD_ + c0 + head * 64 + e8] = val;
            } else {
                _Float16* dst = (g == 0) ? qh : (g == 1) ? kh : vh;
                const int hh = (c0 >> 6) + head;
                *(f16x8*)&dst[((size_t)hh * N_ + m0 + r) * D_ + e8] = val;
            }
        }
    }
}

// ---------------------------------------------------------------------------
// Kernel 2: local attention via fp16 MFMA. One block per (h,t), 4 waves.
// XCD swizzle, single K-stage (R10). R11: V^T staging packs 4 slot-values
// per ds_write_b64 (8 writes/thread, was 32 scalar b16).
// ---------------------------------------------------------------------------
__global__ __launch_bounds__(256, 4) void attn_mfma(
    const _Float16* __restrict__ qh, const _Float16* __restrict__ kh,
    const _Float16* __restrict__ vh, const float* __restrict__ bias,
    const _Float16* __restrict__ gh, _Float16* __restrict__ of)
{
    __shared__ __align__(16) char smem[40960];
    _Float16* Qs = (_Float16*)smem;              // phase A: [64][64] swz, 8 KB
    char* Ks = smem + 8192;                      // phase A: [256][64] swz, 32 KB
    _Float16* Ps = (_Float16*)smem;              // phase B: [64][136], 17408 B
    _Float16* Vs = (_Float16*)(smem + 17408);    // phase B: [64][136], 17408 B
    float* Oe = (float*)smem;                    // epi: [64][68] fp32

    const int lb  = blockIdx.x;
    const int xcd = lb & 7;
    const int j_  = lb >> 3;
    const int h   = j_ >> 3;
    const int t   = xcd * 8 + (j_ & 7);
    const int tid = threadIdx.x;
    const int lane = tid & 63;
    const int wv = tid >> 6;
    const int frow = lane & 15;
    const int grp = lane >> 4;
    const int kbase = t * 64 - 96;

    const char* qbase = (const char*)qh + (size_t)(h * N_ + t * 64) * 128;
    const char* kbase_p = (const char*)kh + (size_t)h * N_ * 128;

    // ---- stage Q (8 KB) + K (32 KB, all 256 slots), async back-to-back ----
#pragma unroll
    for (int q = 0; q < 2; ++q) {
        const int lin = q * 4096 + tid * 16;
        const int row = lin >> 7;
        const int ch = (lin >> 4) & 7;
        gload16(qbase + row * 128 + ((ch ^ (row & 7)) << 4), (char*)Qs + lin);
    }
#pragma unroll
    for (int q = 0; q < 8; ++q) {
        const int lin = q * 4096 + tid * 16;
        const int row = lin >> 7;              // 0..255
        const int ch = (lin >> 4) & 7;
        const int kg = kbase + row;
        if ((unsigned)kg < (unsigned)N_) {
            gload16(kbase_p + (size_t)kg * 128 + ((ch ^ (row & 7)) << 4), Ks + lin);
        } else {
            *(float4*)(Ks + lin) = make_float4(0.f, 0.f, 0.f, 0.f);
        }
    }

    // ---- bias -> accumulator init (all 256 slots) ----
    f32x4 sacc[16];
    {
        const int rowg = t * 64 + wv * 16 + grp * 4;
#pragma unroll
        for (int j = 0; j < 16; ++j) {
            const int colg = kbase + j * 16 + frow;
            const bool ok = (unsigned)colg < (unsigned)N_;
#pragma unroll
            for (int v = 0; v < 4; ++v)
                sacc[j][v] = ok ? bias[(size_t)(rowg + v) * N_ + colg] : 0.f;
        }
    }
    __syncthreads();   // Q+K staged

    // ---- QK: 32 MFMAs, one barrier ----
    {
        const int rq = wv * 16 + frow;
#pragma unroll
        for (int ks = 0; ks < 2; ++ks) {
            const f16x8 aq = *(const f16x8*)((char*)Qs + rq * 128 + (((ks * 4 + grp) ^ (rq & 7)) << 4));
#pragma unroll
            for (int j = 0; j < 16; ++j) {
                const int rk = j * 16 + frow;     // slot 0..255
                const f16x8 bk = *(const f16x8*)(Ks + rk * 128 + (((ks * 4 + grp) ^ (rk & 7)) << 4));
                sacc[j] = __builtin_amdgcn_mfma_f32_16x16x32_f16(aq, bk, sacc[j], 0, 0, 0);
            }
        }
    }
    __syncthreads();   // Q/K dead; phase B may overlay

    // ---- softmax over 256 slots/row ----
    float inv[4];
#pragma unroll
    for (int v = 0; v < 4; ++v) {
        float m = sacc[0][v];
#pragma unroll
        for (int f = 1; f < 16; ++f) m = fmaxf(m, sacc[f][v]);
        m = fmaxf(m, __shfl_xor(m, 1));
        m = fmaxf(m, __shfl_xor(m, 2));
        m = fmaxf(m, __shfl_xor(m, 4));
        m = fmaxf(m, __shfl_xor(m, 8));
        float l = 0.f;
#pragma unroll
        for (int f = 0; f < 16; ++f) {
            float e = __expf(sacc[f][v] - m);
            sacc[f][v] = e;
            l += e;
        }
        l += __shfl_xor(l, 1);
        l += __shfl_xor(l, 2);
        l += __shfl_xor(l, 4);
        l += __shfl_xor(l, 8);
        inv[v] = 1.f / l;
    }

    // ---- PV over 2 slot-chunks of 128; P written per-chunk from sacc ----
    f32x4 oacc[4];
#pragma unroll
    for (int jd = 0; jd < 4; ++jd) oacc[jd] = (f32x4){0.f, 0.f, 0.f, 0.f};

#pragma unroll
    for (int c = 0; c < 2; ++c) {
        // stage V^T chunk: Vs[d][sl]; thread = 4 slots x 8 d, b64 packed writes
        {
            const int sg = tid >> 3;          // 0..31 -> slots sg*4..+4
            const int dg = tid & 7;           // d-block dg*8..+8
            const int s0 = sg * 4;
            f16x8 vrow[4];
#pragma unroll
            for (int i = 0; i < 4; ++i) {
                const int kg = kbase + c * 128 + s0 + i;
                if ((unsigned)kg < (unsigned)N_) {
                    vrow[i] = *(const f16x8*)(vh + ((size_t)h * N_ + kg) * D_ + dg * 8);
                } else {
#pragma unroll
                    for (int e = 0; e < 8; ++e) vrow[i][e] = (_Float16)0.f;
                }
            }
#pragma unroll
            for (int e = 0; e < 8; ++e) {
                const int d = dg * 8 + e;
                f16x4 pk;
                pk[0] = vrow[0][e]; pk[1] = vrow[1][e];
                pk[2] = vrow[2][e]; pk[3] = vrow[3][e];
                *(f16x4*)&Vs[d * 136 + s0] = pk;
            }
        }
        // write this chunk's unnormalized P (sacc[c*8+j] = slot c*128+j*16+frow)
        {
            const int rb = wv * 16 + grp * 4;
#pragma unroll
            for (int j = 0; j < 8; ++j) {
                const int col = j * 16 + frow;
#pragma unroll
                for (int v = 0; v < 4; ++v)
                    Ps[(rb + v) * 136 + col] = (_Float16)sacc[c * 8 + j][v];
            }
        }
        __syncthreads();   // Ps + Vs ready
        const int rp = wv * 16 + frow;
#pragma unroll
        for (int ks = 0; ks < 4; ++ks) {
            const f16x8 ap = *(const f16x8*)((char*)Ps + rp * 272 + ks * 64 + grp * 16);
#pragma unroll
            for (int jd = 0; jd < 4; ++jd) {
                const f16x8 bv = *(const f16x8*)((char*)Vs + (jd * 16 + frow) * 272 + ks * 64 + grp * 16);
                oacc[jd] = __builtin_amdgcn_mfma_f32_16x16x32_f16(ap, bv, oacc[jd], 0, 0, 0);
            }
        }
        __syncthreads();   // Ps/Vs reads done before restage / epi overlay
    }

    // ---- epilogue: O*inv -> LDS fp32 [64][68]; readback * gate -> fp16 ----
#pragma unroll
    for (int jd = 0; jd < 4; ++jd) {
        const int dcol = jd * 16 + frow;
#pragma unroll
        for (int v = 0; v < 4; ++v) {
            const int rn = wv * 16 + grp * 4 + v;
            Oe[rn * 68 + dcol] = oacc[jd][v] * inv[v];
        }
    }
    __syncthreads();
    {
        const int r   = tid >> 2;
        const int seg = tid & 3;
        const int n   = t * 64 + r;
        const int cg0 = h * 64 + seg * 16;
        const float* orow = &Oe[r * 68 + seg * 16];
        f32x4 o0 = *(const f32x4*)&orow[0];
        f32x4 o1 = *(const f32x4*)&orow[4];
        f32x4 o2 = *(const f32x4*)&orow[8];
        f32x4 o3 = *(const f32x4*)&orow[12];
        const f16x8 g0 = *(const f16x8*)&gh[(size_t)n * HD_ + cg0];
        const f16x8 g1 = *(const f16x8*)&gh[(size_t)n * HD_ + cg0 + 8];
        f16x8 r0, r1;
#pragma unroll
        for (int e = 0; e < 4; ++e) {
            r0[e]     = (_Float16)(o0[e] * (float)g0[e]);
            r0[4 + e] = (_Float16)(o1[e] * (float)g0[4 + e]);
            r1[e]     = (_Float16)(o2[e] * (float)g1[e]);
            r1[4 + e] = (_Float16)(o3[e] * (float)g1[4 + e]);
        }
        *(f16x8*)&of[(size_t)n * HD_ + cg0]     = r0;
        *(f16x8*)&of[(size_t)n * HD_ + cg0 + 8] = r1;
    }
}

// ---------------------------------------------------------------------------
// Kernel 3: out = (o*g)[4096x1024] @ Wo[1024x256], fp16 MFMA. 32x64 tiles,
// 512 blocks = 2/CU, BK=64, XOR-8 swizzle, XCD swizzle. (unchanged from R10)
// ---------------------------------------------------------------------------
__global__ __launch_bounds__(256) void out_mfma(
    const _Float16* __restrict__ of, const _Float16* __restrict__ WoTf,
    float* __restrict__ out)
{
    __shared__ __align__(16) _Float16 smem[2048 + 4096];  // As [32][64] 4KB, Bs [64][64] 8KB
    _Float16* As = smem;
    _Float16* Bs = smem + 2048;

    const int lb  = blockIdx.x;
    const int xcd = lb & 7;
    const int s   = lb >> 3;                 // 0..63
    const int rowt = (s >> 2) * 8 + xcd;     // 0..127
    const int m0  = rowt * 32;
    const int c0  = (s & 3) * 64;

    const int tid  = threadIdx.x;
    const int wave = tid >> 6;
    const int lane = tid & 63;
    const int wr   = wave >> 1;
    const int wc   = wave & 1;
    const int frow = lane & 15;
    const int grp  = lane >> 4;

    f32x4 acc[2];
#pragma unroll
    for (int j = 0; j < 2; ++j) acc[j] = (f32x4){0.f, 0.f, 0.f, 0.f};

    for (int kt = 0; kt < 1024; kt += 64) {
        __syncthreads();
        {   // A: 32 rows x 64 k = 4 KB = 1 chunk/thread
            const int row = tid >> 3;            // 0..31
            const int ch  = tid & 7;
            const int koff = kt + ((ch ^ (row & 7)) << 3);
            gload16(of + (size_t)(m0 + row) * HD_ + koff, (char*)As + tid * 16);
        }
#pragma unroll
        for (int p = 0; p < 2; ++p) {            // B: 64 rows x 64 k = 8 KB
            const int lin = p * 4096 + tid * 16;
            const int row = lin >> 7;            // 0..63
            const int ch  = (lin >> 4) & 7;
            const int koff = kt + ((ch ^ (row & 7)) << 3);
            gload16(WoTf + (size_t)(c0 + row) * HD_ + koff, (char*)Bs + lin);
        }
        __syncthreads();

#pragma unroll
        for (int ks = 0; ks < 2; ++ks) {
            const int ra = wr * 16 + frow;
            const f16x8 af = *(const f16x8*)((char*)As + ra * 128 + (((ks * 4 + grp) ^ (ra & 7)) << 4));
#pragma unroll
            for (int j = 0; j < 2; ++j) {
                const int rb = wc * 32 + j * 16 + frow;
                const f16x8 bf = *(const f16x8*)((char*)Bs + rb * 128 + (((ks * 4 + grp) ^ (rb & 7)) << 4));
                acc[j] = __builtin_amdgcn_mfma_f32_16x16x32_f16(af, bf, acc[j], 0, 0, 0);
            }
        }
    }

    const int rbase = grp * 4;
#pragma unroll
    for (int j = 0; j < 2; ++j) {
        const int c = c0 + wc * 32 + j * 16 + frow;
#pragma unroll
        for (int v = 0; v < 4; ++v) {
            const int n = m0 + wr * 16 + rbase + v;
            out[(size_t)n * C_ + c] = acc[j][v];
        }
    }
}

// ---------------------------------------------------------------------------
extern "C" void kernel_launch(void* const* d_in, const int* in_sizes, int n_in,
                              void* d_out, int out_size, void* d_ws, size_t ws_size,
                              hipStream_t stream)
{
    const float* q_x  = (const float*)d_in[0];
    const float* kv_x = (const float*)d_in[1];
    const float* bias = (const float*)d_in[2];
    const float* Wq   = (const float*)d_in[3];
    const float* Wk   = (const float*)d_in[4];
    const float* Wv   = (const float*)d_in[5];
    const float* Wg   = (const float*)d_in[6];
    const float* Wo   = (const float*)d_in[7];
    float* out = (float*)d_out;

    char* ws = (char*)d_ws;
    const size_t MB = 1048576;
    _Float16* qh   = (_Float16*)(ws);             // [16][4096][64] fp16, pre-scaled 1/8
    _Float16* kh   = (_Float16*)(ws + 8  * MB);
    _Float16* vh   = (_Float16*)(ws + 16 * MB);
    _Float16* gh   = (_Float16*)(ws + 24 * MB);   // [4096][1024] fp16 sigmoid gate
    _Float16* of   = (_Float16*)(ws + 32 * MB);   // [4096][1024] fp16 gated attn out
    _Float16* WTf  = (_Float16*)(ws + 40 * MB);   // [4][1024][256] fp16
    _Float16* WoTf = (_Float16*)(ws + 42 * MB);   // [256][1024] fp16

    convert_kernel<<<320, 256, 0, stream>>>(Wq, Wk, Wv, Wg, Wo, WTf, WoTf);
    proj_mfma<<<1024, 256, 0, stream>>>(q_x, kv_x, WTf, qh, kh, vh, gh);
    attn_mfma<<<1024, 256, 0, stream>>>(qh, kh, vh, bias, gh, of);
    out_mfma<<<512, 256, 0, stream>>>(of, WoTf, out);
}